// Round 1
// baseline (139.324 us; speedup 1.0000x reference)
//
#include <hip/hip_runtime.h>

// StructOnlyClassifier: per-graph node-type histogram (segment_sum over sorted
// batch ids) + tiny MLP. x (d_in[0]) is UNUSED by the reference.
//
// Kernel 1: packed-u64 histogram. bits [0:16)=count(nt==0), [16:32)=count(nt==1),
//           [32:48)=count(nt==2), [48:64)=total. One atomicAdd per graph-run.
// Kernel 2: per-graph 4->32->16->1 MLP, weights in LDS.

constexpr int QUADS_PER_THREAD = 8;   // each thread handles 8 int4 quads = 32 nodes

__global__ __launch_bounds__(256) void hist_kernel(
    const int* __restrict__ batch, const int* __restrict__ ntype,
    unsigned long long* __restrict__ hist, int n_quads)
{
    const int t    = blockIdx.x * blockDim.x + threadIdx.x;
    const int wave = t >> 6;
    const int lane = t & 63;
    // wave owns a contiguous region of 64*QUADS_PER_THREAD quads; lane-contiguous
    // addressing per iteration -> perfectly coalesced 16B/lane loads.
    const long long base = (long long)wave * (64 * QUADS_PER_THREAD) + lane;

    const int4* b4 = (const int4*)batch;
    const int4* t4 = (const int4*)ntype;

    unsigned long long acc = 0;
    int cur = -1;

    #pragma unroll
    for (int j = 0; j < QUADS_PER_THREAD; ++j) {
        long long q = base + (long long)j * 64;
        if (q < n_quads) {
            int4 b  = b4[q];
            int4 nt = t4[q];
            int bs[4] = {b.x, b.y, b.z, b.w};
            int ts[4] = {nt.x, nt.y, nt.z, nt.w};
            #pragma unroll
            for (int k = 0; k < 4; ++k) {
                int bk = bs[k];
                if (bk != cur) {
                    if (acc) atomicAdd(&hist[cur], acc);
                    cur = bk;
                    acc = 0ull;
                }
                acc += (1ull << (ts[k] * 16)) | (1ull << 48);
            }
        }
    }
    if (acc) atomicAdd(&hist[cur], acc);
}

__global__ __launch_bounds__(256) void mlp_kernel(
    const unsigned long long* __restrict__ hist,
    const float* __restrict__ W1, const float* __restrict__ b1,
    const float* __restrict__ W2, const float* __restrict__ b2,
    const float* __restrict__ W3, const float* __restrict__ b3,
    float* __restrict__ out, int B)
{
    __shared__ float sW1[128], sb1[32], sW2[512], sb2[16], sW3[16], sb3[1];
    const int tid = threadIdx.x;
    for (int i = tid; i < 128; i += 256) sW1[i] = W1[i];
    for (int i = tid; i < 512; i += 256) sW2[i] = W2[i];
    if (tid < 32)  sb1[tid] = b1[tid];
    if (tid < 16)  sb2[tid] = b2[tid];
    if (tid >= 32 && tid < 48) sW3[tid - 32] = W3[tid - 32];
    if (tid == 0)  sb3[0] = b3[0];
    __syncthreads();

    const int g = blockIdx.x * blockDim.x + tid;
    if (g >= B) return;

    const unsigned long long h = hist[g];
    const float f0 = (float)(int)( h        & 0xFFFFull) - 54.5f;
    const float f1 = (float)(int)((h >> 16) & 0xFFFFull);
    const float f2 = (float)(int)((h >> 32) & 0xFFFFull);
    const float f3 = (float)(int)( h >> 48)              - 56.5f;

    float h1[32];
    #pragma unroll
    for (int j = 0; j < 32; ++j) {
        float s = sb1[j];
        s = fmaf(f0, sW1[      j], s);
        s = fmaf(f1, sW1[ 32 + j], s);
        s = fmaf(f2, sW1[ 64 + j], s);
        s = fmaf(f3, sW1[ 96 + j], s);
        h1[j] = fmaxf(0.0f, s);
    }

    float h2[16];
    #pragma unroll
    for (int m = 0; m < 16; ++m) {
        float s = sb2[m];
        #pragma unroll
        for (int j = 0; j < 32; ++j)
            s = fmaf(h1[j], sW2[j * 16 + m], s);
        h2[m] = fmaxf(0.0f, s);
    }

    float o = sb3[0];
    #pragma unroll
    for (int m = 0; m < 16; ++m)
        o = fmaf(h2[m], sW3[m], o);

    out[g] = o;
}

extern "C" void kernel_launch(void* const* d_in, const int* in_sizes, int n_in,
                              void* d_out, int out_size, void* d_ws, size_t ws_size,
                              hipStream_t stream) {
    // inputs: 0:x(N) 1:batch(N) 2:node_type(N) 3:num_graphs 4:W1 5:b1 6:W2 7:b2 8:W3 9:b3
    const int*   batch = (const int*)d_in[1];
    const int*   ntype = (const int*)d_in[2];
    const float* W1    = (const float*)d_in[4];
    const float* b1    = (const float*)d_in[5];
    const float* W2    = (const float*)d_in[6];
    const float* b2    = (const float*)d_in[7];
    const float* W3    = (const float*)d_in[8];
    const float* b3    = (const float*)d_in[9];
    float*       out   = (float*)d_out;

    const int n = in_sizes[1];          // 16,777,216 nodes
    const int B = out_size;             // 16,384 graphs

    unsigned long long* hist = (unsigned long long*)d_ws;
    hipMemsetAsync(d_ws, 0, (size_t)B * sizeof(unsigned long long), stream);

    const int n_quads = n / 4;                                  // 4,194,304
    const int total_threads = (n_quads + QUADS_PER_THREAD - 1) / QUADS_PER_THREAD;
    const int blocks = (total_threads + 255) / 256;             // 2048 blocks
    hist_kernel<<<blocks, 256, 0, stream>>>(batch, ntype, hist, n_quads);

    mlp_kernel<<<(B + 255) / 256, 256, 0, stream>>>(hist, W1, b1, W2, b2, W3, b3, out, B);
}